// Round 6
// baseline (123.478 us; speedup 1.0000x reference)
//
#include <hip/hip_runtime.h>
#include <hip/hip_bf16.h>

typedef __bf16 bf16_t;
typedef bf16_t bf16x8 __attribute__((ext_vector_type(8)));
typedef bf16_t bf16x4 __attribute__((ext_vector_type(4)));
typedef float  floatx4 __attribute__((ext_vector_type(4)));

#define NROWS 65536
#define NCENT 512
#define NDIM  128
#define BM    128          // rows per block (and per wave)
#define NBLKS (NROWS / BM) // 512 blocks x 256 thr = 2048 waves = exactly 8/CU resident

// d_ws: [0,131072) mu bf16 frag-major; [131072,133120) h2 = 0.5*|mu_bf16|^2 float[512]
// frag-major addr(col,k) = jg*2048 + kk*512 + quad*128 + l16*8 + e
//   col = jg*16 + l16, k = kk*32 + quad*8 + e
// -> a wave's B-frag b128 load (lane=(l16,quad)) is 1KB lane-contiguous: perfectly coalesced.

__global__ __launch_bounds__(256)
void mu_pack_kernel(const float* __restrict__ mu, bf16_t* __restrict__ ws_mu,
                    float* __restrict__ ws_h2)
{
    const int tid = threadIdx.x;
    const int col_local = tid >> 5;     // 8 cols per block
    const int j = tid & 31;             // 32 threads per col, 4 floats each
    const int col = blockIdx.x * 8 + col_local;
    const float4 v = *(const float4*)(mu + col * NDIM + j * 4);
    bf16x4 pk = {(bf16_t)v.x, (bf16_t)v.y, (bf16_t)v.z, (bf16_t)v.w};
    const int k0 = j * 4;
    const int kk = k0 >> 5, quad = (k0 >> 3) & 3, e0 = k0 & 7;
    const int jg = col >> 4, c16 = col & 15;
    *(bf16x4*)(ws_mu + jg*2048 + kk*512 + quad*128 + c16*8 + e0) = pk;
    float f0=(float)pk[0], f1=(float)pk[1], f2=(float)pk[2], f3=(float)pk[3];
    float s = f0*f0 + f1*f1 + f2*f2 + f3*f3;
    s += __shfl_xor(s, 1);  s += __shfl_xor(s, 2);  s += __shfl_xor(s, 4);
    s += __shfl_xor(s, 8);  s += __shfl_xor(s, 16);
    if (j == 0) ws_h2[col] = 0.5f * s;
}

// Wave w covers cols [w*128, w*128+128); all 4 waves cover all 128 rows of the block.
__global__ __launch_bounds__(256, 2)   // 2 blocks/CU -> 2 waves/SIMD -> 256-VGPR budget
void kmeans_main(const float* __restrict__ z, const bf16_t* __restrict__ ws_mu,
                 const float* __restrict__ ws_h2, float* __restrict__ out)
{
    __shared__ float rmx[4][BM];    // per-wave row maxes (2 KB)
    __shared__ float z2row[BM];     // 512 B
    __shared__ float vsum[BM];      // 512 B

    const int tid  = threadIdx.x;
    const int lane = tid & 63;
    const int w    = tid >> 6;
    const int quad = lane >> 4;
    const int l16  = lane & 15;
    const size_t rowbase = (size_t)blockIdx.x * BM;

    // ---- A fragments: 128 rows straight from global fp32, cvt bf16 in regs ----
    // lane (l16,quad), set i: row = i*16+l16, k-slice = quad*8+e + kk*32
    bf16x8 afr[8][4];
#pragma unroll
    for (int i = 0; i < 8; ++i) {
        const float* rp = z + (rowbase + i*16 + l16) * NDIM + quad*8;
        float ss = 0.f;
#pragma unroll
        for (int kk = 0; kk < 4; ++kk) {
            float4 a = *(const float4*)(rp + kk*32);
            float4 b = *(const float4*)(rp + kk*32 + 4);
            bf16x8 pk = {(bf16_t)a.x, (bf16_t)a.y, (bf16_t)a.z, (bf16_t)a.w,
                         (bf16_t)b.x, (bf16_t)b.y, (bf16_t)b.z, (bf16_t)b.w};
            afr[i][kk] = pk;
#pragma unroll
            for (int e = 0; e < 8; ++e) { float f = (float)pk[e]; ss = fmaf(f, f, ss); }
        }
        ss += __shfl_xor(ss, 16);     // sum quad partials -> full |z_row|^2
        ss += __shfl_xor(ss, 32);
        if (w == 0 && quad == 0) z2row[i*16 + l16] = ss;   // straight to LDS, no regs
    }

    // ---- h2 for this wave's 8 col-groups (L2-hit, 8 regs) ----
    float h2a[8];
#pragma unroll
    for (int j2 = 0; j2 < 8; ++j2)
        h2a[j2] = ws_h2[(w*8 + j2)*16 + l16];

    // ---- stream B from L2, double-buffered; pure-register MFMA loop ----
    const bf16_t* bbase = ws_mu + (size_t)w*8*2048 + quad*128 + l16*8;
    bf16x8 bb[2][4];
#pragma unroll
    for (int kk = 0; kk < 4; ++kk)
        bb[0][kk] = *(const bf16x8*)(bbase + kk*512);

    float tm[8][4];
#pragma unroll
    for (int i = 0; i < 8; ++i)
#pragma unroll
        for (int r = 0; r < 4; ++r) tm[i][r] = -3.0e38f;

#pragma unroll
    for (int j2 = 0; j2 < 8; ++j2) {
        const int cb = j2 & 1;
        if (j2 < 7) {
            const bf16_t* nb = bbase + (size_t)(j2 + 1)*2048;
#pragma unroll
            for (int kk = 0; kk < 4; ++kk)
                bb[cb ^ 1][kk] = *(const bf16x8*)(nb + kk*512);
        }
        const float mh = -h2a[j2];            // acc-init = -0.5*|mu_col|^2
#pragma unroll
        for (int i = 0; i < 8; ++i) {         // 8 independent acc chains
            floatx4 acc = (floatx4){mh, mh, mh, mh};
#pragma unroll
            for (int kk = 0; kk < 4; ++kk)
                acc = __builtin_amdgcn_mfma_f32_16x16x32_bf16(
                    afr[i][kk], bb[cb][kk], acc, 0, 0, 0);
#pragma unroll
            for (int r = 0; r < 4; ++r)
                tm[i][r] = fmaxf(tm[i][r], acc[r]);   // max(dot - h2): deferred sqrt
        }
    }

    // ---- per-row max over this wave's 128 cols (xor over l16), publish ----
#pragma unroll
    for (int i = 0; i < 8; ++i)
#pragma unroll
        for (int r = 0; r < 4; ++r) {
            float v = tm[i][r];
            v = fmaxf(v, __shfl_xor(v, 1));
            v = fmaxf(v, __shfl_xor(v, 2));
            v = fmaxf(v, __shfl_xor(v, 4));
            v = fmaxf(v, __shfl_xor(v, 8));
            if (l16 == 0) rmx[w][i*16 + quad*4 + r] = v;
        }
    __syncthreads();

    // ---- one sqrt per row ----
    if (tid < BM) {
        float m  = fmaxf(fmaxf(rmx[0][tid], rmx[1][tid]),
                         fmaxf(rmx[2][tid], rmx[3][tid]));
        float d2 = z2row[tid] - 2.0f * m;
        vsum[tid] = sqrtf(fmaxf(d2, 0.f));
    }
    __syncthreads();

    // ---- block sum of 128 row distances, one atomic ----
    if (tid < 64) {
        float v = vsum[tid] + vsum[tid + 64];
#pragma unroll
        for (int off = 32; off; off >>= 1) v += __shfl_down(v, off);
        if (tid == 0) atomicAdd(out, v * (1.0f / 65536.0f));
    }
}

extern "C" void kernel_launch(void* const* d_in, const int* in_sizes, int n_in,
                              void* d_out, int out_size, void* d_ws, size_t ws_size,
                              hipStream_t stream) {
    const float* z  = (const float*)d_in[0];
    const float* mu = (const float*)d_in[1];
    float* out = (float*)d_out;
    bf16_t* ws_mu = (bf16_t*)d_ws;
    float* ws_h2 = (float*)((char*)d_ws + 131072);
    hipMemsetAsync(out, 0, sizeof(float), stream);   // d_out is poisoned 0xAA
    mu_pack_kernel<<<dim3(64), dim3(256), 0, stream>>>(mu, ws_mu, ws_h2);
    kmeans_main<<<dim3(NBLKS), dim3(256), 0, stream>>>(z, ws_mu, ws_h2, out);
}

// Round 7
// 97.525 us; speedup vs baseline: 1.2661x; 1.2661x over previous
//
#include <hip/hip_runtime.h>
#include <hip/hip_bf16.h>

typedef __bf16 bf16_t;
typedef bf16_t bf16x8 __attribute__((ext_vector_type(8)));
typedef float  floatx4 __attribute__((ext_vector_type(4)));

#define NROWS 65536
#define NDIM  128
#define BM    64
#define TILES 4
#define ZPITCH 136   // 272-B row pitch: 16B-aligned b128, 2-way (free) bank aliasing

// d_ws: t0[65536] | t1[65536] | z2[65536]  (floats; t = max_col(dot - 0.5*|mu|^2) per flavor)

// Block: 256 thr = 4 waves; wave w covers cols flavor*256 + w*64 .. +63 (B in regs, 64 VGPRs).
// Rows: 4 tiles of 64; A staged LDS (no-spill path), pf prefetch under MFMA.
__global__ __launch_bounds__(256, 2)
void kmeans_main(const float* __restrict__ z, const float* __restrict__ mu,
                 float* __restrict__ ws_t0, float* __restrict__ ws_t1,
                 float* __restrict__ ws_z2)
{
    __shared__ bf16_t ztile[BM * ZPITCH];   // 17408 B
    __shared__ float rmx[4][BM];            // 1024 B  -> ~18.5 KB total

    const int tid   = threadIdx.x;
    const int lane  = tid & 63;
    const int w     = tid >> 6;
    const int quad  = lane >> 4;
    const int l16   = lane & 15;
    const int rowblk  = blockIdx.x >> 1;
    const int flavor  = blockIdx.x & 1;      // adjacent blockIdx share z -> L2/L3 hit
    float* wt = flavor ? ws_t1 : ws_t0;
    const int cb = flavor * 256 + w * 64;    // this wave's column base
    const size_t rt0 = (size_t)rowblk * TILES;

    // ---- issue z prefetch for tile 0 first (HBM latency overlaps B prologue) ----
    float4 pf[8];   // 32 B/lane contiguous: unit q8=it*256+tid -> zsrc[2q8], zsrc[2q8+1]
    {
        const float4* zsrc = (const float4*)(z + rt0 * BM * NDIM);
#pragma unroll
        for (int it = 0; it < 4; ++it) {
            int q8 = it * 256 + tid;
            pf[2*it]   = zsrc[2*q8];
            pf[2*it+1] = zsrc[2*q8 + 1];
        }
    }

    // ---- B prologue: 4 col-groups, cvt fp32->bf16 in regs, h2 folded; 64 regs ----
    bf16x8 bfr[4][4];
    float  h2a[4];
#pragma unroll
    for (int g = 0; g < 4; ++g) {
        const float* cp = mu + (size_t)(cb + g*16 + l16) * NDIM + quad*8;
        float ss = 0.f;
#pragma unroll
        for (int kk = 0; kk < 4; ++kk) {
            float4 a = *(const float4*)(cp + kk*32);
            float4 b = *(const float4*)(cp + kk*32 + 4);
            bf16x8 pk = {(bf16_t)a.x, (bf16_t)a.y, (bf16_t)a.z, (bf16_t)a.w,
                         (bf16_t)b.x, (bf16_t)b.y, (bf16_t)b.z, (bf16_t)b.w};
            bfr[g][kk] = pk;
#pragma unroll
            for (int e = 0; e < 8; ++e) { float f = (float)pk[e]; ss = fmaf(f, f, ss); }
        }
        ss += __shfl_xor(ss, 16);   // sum quad partials -> full |mu_col|^2
        ss += __shfl_xor(ss, 32);
        h2a[g] = 0.5f * ss;
    }

#pragma unroll 1
    for (int t = 0; t < TILES; ++t) {
        const size_t rowbase = (rt0 + t) * BM;

        // ---- stage ztile from pf: cvt + b128 write + z2 (flavor 0 stores z2) ----
#pragma unroll
        for (int it = 0; it < 4; ++it) {
            int q8 = it * 256 + tid;          // r = q8>>4 (16 units/row), u = q8&15
            int r = q8 >> 4, u = q8 & 15;
            float4 va = pf[2*it], vb = pf[2*it+1];
            bf16x8 pk = {(bf16_t)va.x, (bf16_t)va.y, (bf16_t)va.z, (bf16_t)va.w,
                         (bf16_t)vb.x, (bf16_t)vb.y, (bf16_t)vb.z, (bf16_t)vb.w};
            *(bf16x8*)&ztile[r * ZPITCH + u * 8] = pk;
            float ss = 0.f;
#pragma unroll
            for (int e = 0; e < 8; ++e) { float f = (float)pk[e]; ss = fmaf(f, f, ss); }
            ss += __shfl_xor(ss, 1); ss += __shfl_xor(ss, 2);
            ss += __shfl_xor(ss, 4); ss += __shfl_xor(ss, 8);
            if (flavor == 0 && (lane & 15) == 0) ws_z2[rowbase + r] = ss;
        }
        __syncthreads();   // B1: ztile visible

        // ---- prefetch tile t+1 (drains under MFMA) ----
        if (t + 1 < TILES) {
            const float4* zsrc = (const float4*)(z + (rt0 + t + 1) * BM * NDIM);
#pragma unroll
            for (int it = 0; it < 4; ++it) {
                int q8 = it * 256 + tid;
                pf[2*it]   = zsrc[2*q8];
                pf[2*it+1] = zsrc[2*q8 + 1];
            }
        }

        // ---- A frags from LDS (the spill-free source), then pure MFMA ----
        bf16x8 afr[4][4];
#pragma unroll
        for (int i = 0; i < 4; ++i)
#pragma unroll
            for (int kk = 0; kk < 4; ++kk)
                afr[i][kk] = *(const bf16x8*)&ztile[(i*16 + l16) * ZPITCH + kk*32 + quad*8];

        float tm[4][4];
#pragma unroll
        for (int i = 0; i < 4; ++i)
#pragma unroll
            for (int r = 0; r < 4; ++r) tm[i][r] = -3.0e38f;

#pragma unroll
        for (int g = 0; g < 4; ++g) {
            const float mh = -h2a[g];          // acc-init = -0.5*|mu_col|^2
#pragma unroll
            for (int i = 0; i < 4; ++i) {      // 4 independent acc chains
                floatx4 acc = (floatx4){mh, mh, mh, mh};
#pragma unroll
                for (int kk = 0; kk < 4; ++kk)
                    acc = __builtin_amdgcn_mfma_f32_16x16x32_bf16(
                        afr[i][kk], bfr[g][kk], acc, 0, 0, 0);
#pragma unroll
                for (int r = 0; r < 4; ++r)
                    tm[i][r] = fmaxf(tm[i][r], acc[r]);   // deferred sqrt
            }
        }

        // ---- per-row max over this wave's 64 cols, publish per wave ----
#pragma unroll
        for (int i = 0; i < 4; ++i)
#pragma unroll
            for (int r = 0; r < 4; ++r) {
                float v = tm[i][r];
                v = fmaxf(v, __shfl_xor(v, 1));
                v = fmaxf(v, __shfl_xor(v, 2));
                v = fmaxf(v, __shfl_xor(v, 4));
                v = fmaxf(v, __shfl_xor(v, 8));
                if (l16 == 0) rmx[w][i*16 + quad*4 + r] = v;
            }
        __syncthreads();   // B2: rmx visible

        if (tid < BM) {
            float m = fmaxf(fmaxf(rmx[0][tid], rmx[1][tid]),
                            fmaxf(rmx[2][tid], rmx[3][tid]));
            wt[rowbase + tid] = m;             // coalesced 256B store per flavor
        }
        __syncthreads();   // B3: rmx/ztile reusable
    }
}

__global__ __launch_bounds__(256)
void kmeans_final(const float* __restrict__ ws_t0, const float* __restrict__ ws_t1,
                  const float* __restrict__ ws_z2, float* __restrict__ out)
{
    __shared__ float red[4];
    const int tid = threadIdx.x;
    const int g = blockIdx.x * 256 + tid;      // 16384 threads x 4 rows
    float4 t0 = ((const float4*)ws_t0)[g];
    float4 t1 = ((const float4*)ws_t1)[g];
    float4 q2 = ((const float4*)ws_z2)[g];
    float s = sqrtf(fmaxf(q2.x - 2.f * fmaxf(t0.x, t1.x), 0.f))
            + sqrtf(fmaxf(q2.y - 2.f * fmaxf(t0.y, t1.y), 0.f))
            + sqrtf(fmaxf(q2.z - 2.f * fmaxf(t0.z, t1.z), 0.f))
            + sqrtf(fmaxf(q2.w - 2.f * fmaxf(t0.w, t1.w), 0.f));
#pragma unroll
    for (int off = 32; off; off >>= 1) s += __shfl_down(s, off);
    if ((tid & 63) == 0) red[tid >> 6] = s;
    __syncthreads();
    if (tid == 0)
        atomicAdd(out, (red[0] + red[1] + red[2] + red[3]) * (1.0f / 65536.0f));
}

extern "C" void kernel_launch(void* const* d_in, const int* in_sizes, int n_in,
                              void* d_out, int out_size, void* d_ws, size_t ws_size,
                              hipStream_t stream) {
    const float* z  = (const float*)d_in[0];
    const float* mu = (const float*)d_in[1];
    float* out = (float*)d_out;
    float* ws_t0 = (float*)d_ws;
    float* ws_t1 = (float*)((char*)d_ws + 262144);
    float* ws_z2 = (float*)((char*)d_ws + 524288);
    hipMemsetAsync(out, 0, sizeof(float), stream);   // d_out poisoned 0xAA
    kmeans_main<<<dim3(512), dim3(256), 0, stream>>>(z, mu, ws_t0, ws_t1, ws_z2);
    kmeans_final<<<dim3(64), dim3(256), 0, stream>>>(ws_t0, ws_t1, ws_z2, out);
}